// Round 15
// baseline (35.498 us; speedup 1.0000x reference)
//
#include <hip/hip_runtime.h>
#include <hip/hip_fp16.h>
#include <math.h>

#define N_DENSE 13
#define N_SPARSE 26
#define SPARSE_DIM 100
#define N_FIELD 39               // 13 + 26 real fields
#define KDIM 16
#define N_FEATURES 2613          // 13 + 26*100
#define ROW_F 624                // real elements per feature row (39*16)
#define ROW_DW 320               // padded half2 per row (40 fields * 8 k-pairs)
#define ROW_U2 160               // uint2 (4 elems) per padded row
#define THREADS 256
#define ROWS_PER_BLOCK 4         // one 64-lane wave per row

// ---------------- pre-pass: fp32 -> half2, padded to 40 fields --------------
#define CVT_TOTAL (N_FEATURES * ROW_U2)
__global__ __launch_bounds__(256) void cvt_pad_f16v(
    const float* __restrict__ v, uint2* __restrict__ o)
{
    int stride = gridDim.x * blockDim.x;
    for (int i = blockIdx.x * blockDim.x + threadIdx.x; i < CVT_TOTAL; i += stride) {
        int n = i / ROW_U2;
        int r = i - n * ROW_U2;      // uint2 index within row
        uint2 w2 = make_uint2(0u, 0u);
        int e = 4 * r;               // first element (of 640 padded; 624 real)
        if (e < ROW_F) {
            float4 f = *reinterpret_cast<const float4*>(v + (size_t)n * ROW_F + e);
            __half2 h0 = __floats2half2_rn(f.x, f.y);
            __half2 h1 = __floats2half2_rn(f.z, f.w);
            w2.x = *reinterpret_cast<unsigned int*>(&h0);
            w2.y = *reinterpret_cast<unsigned int*>(&h1);
        }
        o[(size_t)n * ROW_U2 + r] = w2;
    }
}

// 20-dword gather payload bank (all indices static after unroll -> registers)
struct G20 { __half2 t[20]; };

__device__ __forceinline__ void issue4(
    const __half2* __restrict__ vb, const float* __restrict__ xr,
    const float* __restrict__ w, int s, int l, G20& g, float& lin)
{
    int i0 = N_DENSE + (s    ) * SPARSE_DIM + (int)xr[N_DENSE + s    ];
    int i1 = N_DENSE + (s + 1) * SPARSE_DIM + (int)xr[N_DENSE + s + 1];
    int i2 = N_DENSE + (s + 2) * SPARSE_DIM + (int)xr[N_DENSE + s + 2];
    int i3 = N_DENSE + (s + 3) * SPARSE_DIM + (int)xr[N_DENSE + s + 3];
    const __half2* b0 = vb + (size_t)i0 * ROW_DW + l;
    const __half2* b1 = vb + (size_t)i1 * ROW_DW + l;
    const __half2* b2 = vb + (size_t)i2 * ROW_DW + l;
    const __half2* b3 = vb + (size_t)i3 * ROW_DW + l;
    g.t[0]  = b0[0]; g.t[1]  = b0[64]; g.t[2]  = b0[128]; g.t[3]  = b0[192]; g.t[4]  = b0[256];
    g.t[5]  = b1[0]; g.t[6]  = b1[64]; g.t[7]  = b1[128]; g.t[8]  = b1[192]; g.t[9]  = b1[256];
    g.t[10] = b2[0]; g.t[11] = b2[64]; g.t[12] = b2[128]; g.t[13] = b2[192]; g.t[14] = b2[256];
    g.t[15] = b3[0]; g.t[16] = b3[64]; g.t[17] = b3[128]; g.t[18] = b3[192]; g.t[19] = b3[256];
    lin += w[i0] + w[i1] + w[i2] + w[i3];
}

__device__ __forceinline__ void issue2(
    const __half2* __restrict__ vb, const float* __restrict__ xr,
    const float* __restrict__ w, int s, int l, G20& g, float& lin)
{
    int i0 = N_DENSE + (s    ) * SPARSE_DIM + (int)xr[N_DENSE + s    ];
    int i1 = N_DENSE + (s + 1) * SPARSE_DIM + (int)xr[N_DENSE + s + 1];
    const __half2* b0 = vb + (size_t)i0 * ROW_DW + l;
    const __half2* b1 = vb + (size_t)i1 * ROW_DW + l;
    g.t[0] = b0[0]; g.t[1] = b0[64]; g.t[2] = b0[128]; g.t[3] = b0[192]; g.t[4] = b0[256];
    g.t[5] = b1[0]; g.t[6] = b1[64]; g.t[7] = b1[128]; g.t[8] = b1[192]; g.t[9] = b1[256];
    lin += w[i0] + w[i1];
}

__device__ __forceinline__ void consume4(const G20& g, __half2 acc[5]) {
#pragma unroll
    for (int f = 0; f < 4; ++f)
#pragma unroll
        for (int m = 0; m < 5; ++m)
            acc[m] = __hadd2(acc[m], g.t[f * 5 + m]);
}

__device__ __forceinline__ void consume2(const G20& g, __half2 acc[5]) {
#pragma unroll
    for (int f = 0; f < 2; ++f)
#pragma unroll
        for (int m = 0; m < 5; ++m)
            acc[m] = __hadd2(acc[m], g.t[f * 5 + m]);
}

// ---------------- main kernel: one wave per batch row -----------------------
// v14 + explicit depth-2 software pipeline: two 20-dword banks (gA/gB);
// group s+1's loads are issued BEFORE group s is consumed, keeping ~40
// dwords outstanding per wave continuously (v14 sawtoothed 20 -> 0 at each
// group boundary). Aggregate in-flight: 6 waves x 40 = 240/SIMD vs v14's
// 7 x 20 = 140.
// launch_bounds(256,6): 85-VGPR cap — 2x20 payload + 5 acc + addr temps.
// (7-wave/73 cap can't hold two banks; hard 8-wave cap spilled in r8.)
__global__ __launch_bounds__(THREADS, 6) void ffm_v15(
    const float* __restrict__ x,     // [B, 39]
    const float* __restrict__ w,     // [2613]
    const float* __restrict__ bias,  // [1]
    const __half2* __restrict__ vb,  // [2613, 320] padded half2 rows
    float* __restrict__ out,         // [B]
    int B)
{
    __shared__ __half2 ldsDense[N_DENSE * ROW_DW];   // 16640 B
    {
        const uint4* src = reinterpret_cast<const uint4*>(vb);
        uint4* dst = reinterpret_cast<uint4*>(ldsDense);
        for (int i = threadIdx.x; i < N_DENSE * ROW_DW / 4; i += THREADS)
            dst[i] = src[i];
    }
    __syncthreads();

    const int l = threadIdx.x & 63;
    // wave-uniform wave id -> uniform row -> x reads become s_loads
    const int wv = __builtin_amdgcn_readfirstlane((int)(threadIdx.x >> 6));
    const int row = blockIdx.x * ROWS_PER_BLOCK + wv;
    if (row >= B) return;

    const float* xr = x + (size_t)row * N_FIELD;

    __half2 acc[5];
#pragma unroll
    for (int m = 0; m < 5; ++m) acc[m] = __floats2half2_rn(0.f, 0.f);

    float lin = bias[0];
    G20 gA, gB;

    // ---- prefetch group 0; dense phase covers its L2 latency ----
    issue4(vb, xr, w, 0, l, gA, lin);

#pragma unroll
    for (int j = 0; j < N_DENSE; ++j) {
        float xv = xr[j];
        lin = fmaf(xv, w[j], lin);
        __half2 xh = __float2half2_rn(xv);
#pragma unroll
        for (int m = 0; m < 5; ++m)
            acc[m] = __hfma2(xh, ldsDense[j * ROW_DW + 64 * m + l], acc[m]);
    }

    // ---- pipelined sparse groups: issue s+1 before consuming s ----
    issue4(vb, xr, w,  4, l, gB, lin);
    consume4(gA, acc);                      // group 0
    issue4(vb, xr, w,  8, l, gA, lin);
    consume4(gB, acc);                      // group 1
    issue4(vb, xr, w, 12, l, gB, lin);
    consume4(gA, acc);                      // group 2
    issue4(vb, xr, w, 16, l, gA, lin);
    consume4(gB, acc);                      // group 3
    issue4(vb, xr, w, 20, l, gB, lin);
    consume4(gA, acc);                      // group 4
    issue2(vb, xr, w, 24, l, gA, lin);      // tail pair into gA[0..9]
    consume4(gB, acc);                      // group 5
    consume2(gA, acc);                      // tail

    // ---- reduction (f32) ----
    float sx = 0.f, sy = 0.f, qx = 0.f, qy = 0.f;
#pragma unroll
    for (int m = 0; m < 5; ++m) {
        float ax = __low2float(acc[m]);
        float ay = __high2float(acc[m]);
        sx += ax; sy += ay;
        qx = fmaf(ax, ax, qx);
        qy = fmaf(ay, ay, qy);
    }
#pragma unroll
    for (int mask = 8; mask <= 32; mask <<= 1) {
        sx += __shfl_xor(sx, mask);
        sy += __shfl_xor(sy, mask);
        qx += __shfl_xor(qx, mask);
        qy += __shfl_xor(qy, mask);
    }
    float c = (sx * sx - qx) + (sy * sy - qy);
    c += __shfl_xor(c, 1);
    c += __shfl_xor(c, 2);
    c += __shfl_xor(c, 4);

    float logit = lin + 0.5f * c;
    if (l == 0) out[row] = 1.f / (1.f + expf(-logit));
}

// ---------------- fp32 fallback (round-1 kernel, 16 lanes/row) --------------
#define ROW_Q (ROW_F / 4)
__global__ __launch_bounds__(256) void ffm_fp32(
    const float* __restrict__ x, const float* __restrict__ w,
    const float* __restrict__ bias, const float* __restrict__ v,
    float* __restrict__ out, int B)
{
    __shared__ float ldsDense[N_DENSE * ROW_F];
    const float4* v4 = reinterpret_cast<const float4*>(v);
    float4* lds4 = reinterpret_cast<float4*>(ldsDense);
    for (int i = threadIdx.x; i < N_DENSE * ROW_Q; i += 256) lds4[i] = v4[i];
    __syncthreads();

    const int g = threadIdx.x >> 4, l = threadIdx.x & 15;
    const int row = blockIdx.x * 16 + g;
    if (row >= B) return;
    const float* xr = x + row * (N_DENSE + N_SPARSE);

    float4 acc[10];
#pragma unroll
    for (int i = 0; i < 10; ++i) acc[i] = make_float4(0.f, 0.f, 0.f, 0.f);
#pragma unroll
    for (int j = 0; j < N_DENSE; ++j) {
        float xv = xr[j];
        const float4* b = lds4 + j * ROW_Q;
#pragma unroll
        for (int i = 0; i < 10; ++i)
            if (i < 9 || l < 12) {
                float4 tt = b[l + 16 * i];
                acc[i].x += xv * tt.x; acc[i].y += xv * tt.y;
                acc[i].z += xv * tt.z; acc[i].w += xv * tt.w;
            }
    }
    int nidx[N_SPARSE];
#pragma unroll
    for (int s = 0; s < N_SPARSE; ++s)
        nidx[s] = N_DENSE + s * SPARSE_DIM + (int)xr[N_DENSE + s];
    for (int s = 0; s < N_SPARSE; ++s) {
        const float4* b = v4 + (size_t)nidx[s] * ROW_Q;
#pragma unroll
        for (int i = 0; i < 10; ++i)
            if (i < 9 || l < 12) {
                float4 tt = b[l + 16 * i];
                acc[i].x += tt.x; acc[i].y += tt.y; acc[i].z += tt.z; acc[i].w += tt.w;
            }
    }
    float4 s4 = make_float4(0,0,0,0), q4 = make_float4(0,0,0,0);
#pragma unroll
    for (int i = 0; i < 10; ++i) {
        s4.x += acc[i].x; s4.y += acc[i].y; s4.z += acc[i].z; s4.w += acc[i].w;
        q4.x += acc[i].x*acc[i].x; q4.y += acc[i].y*acc[i].y;
        q4.z += acc[i].z*acc[i].z; q4.w += acc[i].w*acc[i].w;
    }
#pragma unroll
    for (int m = 4; m <= 8; m <<= 1) {
        s4.x += __shfl_xor(s4.x,m); s4.y += __shfl_xor(s4.y,m);
        s4.z += __shfl_xor(s4.z,m); s4.w += __shfl_xor(s4.w,m);
        q4.x += __shfl_xor(q4.x,m); q4.y += __shfl_xor(q4.y,m);
        q4.z += __shfl_xor(q4.z,m); q4.w += __shfl_xor(q4.w,m);
    }
    float c = (s4.x*s4.x - q4.x) + (s4.y*s4.y - q4.y) +
              (s4.z*s4.z - q4.z) + (s4.w*s4.w - q4.w);
    c += __shfl_xor(c,1); c += __shfl_xor(c,2);
    float lin = bias[0];
#pragma unroll
    for (int j = 0; j < N_DENSE; ++j) lin += xr[j]*w[j];
#pragma unroll
    for (int s = 0; s < N_SPARSE; ++s) lin += w[nidx[s]];
    float logit = lin + 0.5f*c;
    if (l == 0) out[row] = 1.f/(1.f+expf(-logit));
}

extern "C" void kernel_launch(void* const* d_in, const int* in_sizes, int n_in,
                              void* d_out, int out_size, void* d_ws, size_t ws_size,
                              hipStream_t stream) {
    const float* x    = (const float*)d_in[0];
    const float* w    = (const float*)d_in[1];
    const float* bias = (const float*)d_in[2];
    const float* v    = (const float*)d_in[3];
    float* out = (float*)d_out;

    int B = in_sizes[0] / (N_DENSE + N_SPARSE);
    size_t need = (size_t)N_FEATURES * ROW_DW * sizeof(__half2);  // 3,344,640 B

    if (ws_size >= need) {
        int cvt_grid = (CVT_TOTAL + 255) / 256;   // 1634 blocks
        cvt_pad_f16v<<<cvt_grid, 256, 0, stream>>>(v, (uint2*)d_ws);
        int grid = (B + ROWS_PER_BLOCK - 1) / ROWS_PER_BLOCK;
        ffm_v15<<<grid, THREADS, 0, stream>>>(
            x, w, bias, (const __half2*)d_ws, out, B);
    } else {
        int grid = (B + 15) / 16;
        ffm_fp32<<<grid, 256, 0, stream>>>(x, w, bias, v, out, B);
    }
}

// Round 16
// 34.906 us; speedup vs baseline: 1.0170x; 1.0170x over previous
//
#include <hip/hip_runtime.h>
#include <hip/hip_fp16.h>
#include <math.h>

#define N_DENSE 13
#define N_SPARSE 26
#define SPARSE_DIM 100
#define N_FIELD 39               // 13 + 26 real fields
#define KDIM 16
#define N_FEATURES 2613          // 13 + 26*100
#define ROW_F 624                // real elements per feature row (39*16)
#define ROW_DW 320               // padded half2 per row (40 fields * 8 k-pairs)
#define ROW_U2 160               // uint2 (4 elems) per padded row
#define THREADS 256
#define ROWS_PER_BLOCK 4         // one 64-lane wave per row

// ---------------- pre-pass: fp32 -> half2, padded to 40 fields --------------
// One uint2 (4 elements) per thread, float4 source reads, 256-thread blocks.
#define CVT_TOTAL (N_FEATURES * ROW_U2)
__global__ __launch_bounds__(256) void cvt_pad_f16v(
    const float* __restrict__ v, uint2* __restrict__ o)
{
    int stride = gridDim.x * blockDim.x;
    for (int i = blockIdx.x * blockDim.x + threadIdx.x; i < CVT_TOTAL; i += stride) {
        int n = i / ROW_U2;
        int r = i - n * ROW_U2;      // uint2 index within row
        uint2 w2 = make_uint2(0u, 0u);
        int e = 4 * r;               // first element (of 640 padded; 624 real)
        if (e < ROW_F) {
            float4 f = *reinterpret_cast<const float4*>(v + (size_t)n * ROW_F + e);
            __half2 h0 = __floats2half2_rn(f.x, f.y);
            __half2 h1 = __floats2half2_rn(f.z, f.w);
            w2.x = *reinterpret_cast<unsigned int*>(&h0);
            w2.y = *reinterpret_cast<unsigned int*>(&h1);
        }
        o[(size_t)n * ROW_U2 + r] = w2;
    }
}

// ---------------- main kernel: one wave per batch row (round-14 champion) ---
// Row image: 320 half2; element d = (field f = d>>3, k-pair j = d&7).
// Lane l owns d = l + 64m (m=0..4): exactly 5 half2, all with j = l&7.
// xor-orbit {8,16,32} of lane l covers all 40 fields once per k-pair ->
// stage-1 shuffles give S(j),Q(j) per lane; stage-2 {1,2,4} sums j-groups.
// Sparse loop: 4 features/group, 20 dword loads in flight. Group 0's loads
// are issued BEFORE the dense loop so the ~300-400 cyc of dense VALU/LDS
// work covers their L2 latency (phase-diversity fix; +4% measured in r14).
// launch_bounds(256,7): 73-VGPR cap (8-wave cap spilled in r8; uncapped
// gave 92 VGPR / 5 waves in r9; depth-2 pipeline at 6 waves regressed in
// r15 -> 7 waves x 20 loads in flight is the measured local optimum).
__global__ __launch_bounds__(THREADS, 7) void ffm_v14(
    const float* __restrict__ x,     // [B, 39]
    const float* __restrict__ w,     // [2613]
    const float* __restrict__ bias,  // [1]
    const __half2* __restrict__ vb,  // [2613, 320] padded half2 rows
    float* __restrict__ out,         // [B]
    int B)
{
    __shared__ __half2 ldsDense[N_DENSE * ROW_DW];   // 16640 B
    {
        const uint4* src = reinterpret_cast<const uint4*>(vb);
        uint4* dst = reinterpret_cast<uint4*>(ldsDense);
        for (int i = threadIdx.x; i < N_DENSE * ROW_DW / 4; i += THREADS)
            dst[i] = src[i];
    }
    __syncthreads();

    const int l = threadIdx.x & 63;
    // wave-uniform wave id -> uniform row -> x reads become s_loads
    const int wv = __builtin_amdgcn_readfirstlane((int)(threadIdx.x >> 6));
    const int row = blockIdx.x * ROWS_PER_BLOCK + wv;
    if (row >= B) return;

    const float* xr = x + (size_t)row * N_FIELD;

    // ---- PREFETCH sparse group 0 (s = 0..3): issue 20 loads now ----
    int i0 = N_DENSE + 0 * SPARSE_DIM + (int)xr[N_DENSE + 0];
    int i1 = N_DENSE + 1 * SPARSE_DIM + (int)xr[N_DENSE + 1];
    int i2 = N_DENSE + 2 * SPARSE_DIM + (int)xr[N_DENSE + 2];
    int i3 = N_DENSE + 3 * SPARSE_DIM + (int)xr[N_DENSE + 3];
    const __half2* pb0 = vb + (size_t)i0 * ROW_DW + l;
    const __half2* pb1 = vb + (size_t)i1 * ROW_DW + l;
    const __half2* pb2 = vb + (size_t)i2 * ROW_DW + l;
    const __half2* pb3 = vb + (size_t)i3 * ROW_DW + l;
    __half2 p00 = pb0[0], p01 = pb0[64], p02 = pb0[128], p03 = pb0[192], p04 = pb0[256];
    __half2 p10 = pb1[0], p11 = pb1[64], p12 = pb1[128], p13 = pb1[192], p14 = pb1[256];
    __half2 p20 = pb2[0], p21 = pb2[64], p22 = pb2[128], p23 = pb2[192], p24 = pb2[256];
    __half2 p30 = pb3[0], p31 = pb3[64], p32 = pb3[128], p33 = pb3[192], p34 = pb3[256];

    __half2 acc[5];
#pragma unroll
    for (int m = 0; m < 5; ++m) acc[m] = __floats2half2_rn(0.f, 0.f);

    float lin = bias[0];

    // ---- dense features (LDS broadcast; covers group-0 L2 latency) ----
#pragma unroll
    for (int j = 0; j < N_DENSE; ++j) {
        float xv = xr[j];
        lin = fmaf(xv, w[j], lin);
        __half2 xh = __float2half2_rn(xv);
#pragma unroll
        for (int m = 0; m < 5; ++m)
            acc[m] = __hfma2(xh, ldsDense[j * ROW_DW + 64 * m + l], acc[m]);
    }

    // ---- consume prefetched group 0 ----
    lin += w[i0] + w[i1] + w[i2] + w[i3];
    acc[0] = __hadd2(acc[0], p00); acc[1] = __hadd2(acc[1], p01);
    acc[2] = __hadd2(acc[2], p02); acc[3] = __hadd2(acc[3], p03);
    acc[4] = __hadd2(acc[4], p04);
    acc[0] = __hadd2(acc[0], p10); acc[1] = __hadd2(acc[1], p11);
    acc[2] = __hadd2(acc[2], p12); acc[3] = __hadd2(acc[3], p13);
    acc[4] = __hadd2(acc[4], p14);
    acc[0] = __hadd2(acc[0], p20); acc[1] = __hadd2(acc[1], p21);
    acc[2] = __hadd2(acc[2], p22); acc[3] = __hadd2(acc[3], p23);
    acc[4] = __hadd2(acc[4], p24);
    acc[0] = __hadd2(acc[0], p30); acc[1] = __hadd2(acc[1], p31);
    acc[2] = __hadd2(acc[2], p32); acc[3] = __hadd2(acc[3], p33);
    acc[4] = __hadd2(acc[4], p34);

    // ---- remaining sparse gathers: 4 features/group, 20 loads in flight ----
#pragma unroll
    for (int s = 4; s < 24; s += 4) {
        int j0 = N_DENSE + (s    ) * SPARSE_DIM + (int)xr[N_DENSE + s    ];
        int j1 = N_DENSE + (s + 1) * SPARSE_DIM + (int)xr[N_DENSE + s + 1];
        int j2 = N_DENSE + (s + 2) * SPARSE_DIM + (int)xr[N_DENSE + s + 2];
        int j3 = N_DENSE + (s + 3) * SPARSE_DIM + (int)xr[N_DENSE + s + 3];
        const __half2* b0 = vb + (size_t)j0 * ROW_DW + l;
        const __half2* b1 = vb + (size_t)j1 * ROW_DW + l;
        const __half2* b2 = vb + (size_t)j2 * ROW_DW + l;
        const __half2* b3 = vb + (size_t)j3 * ROW_DW + l;
        __half2 t00 = b0[0], t01 = b0[64], t02 = b0[128], t03 = b0[192], t04 = b0[256];
        __half2 t10 = b1[0], t11 = b1[64], t12 = b1[128], t13 = b1[192], t14 = b1[256];
        __half2 t20 = b2[0], t21 = b2[64], t22 = b2[128], t23 = b2[192], t24 = b2[256];
        __half2 t30 = b3[0], t31 = b3[64], t32 = b3[128], t33 = b3[192], t34 = b3[256];
        lin += w[j0] + w[j1] + w[j2] + w[j3];
        acc[0] = __hadd2(acc[0], t00); acc[1] = __hadd2(acc[1], t01);
        acc[2] = __hadd2(acc[2], t02); acc[3] = __hadd2(acc[3], t03);
        acc[4] = __hadd2(acc[4], t04);
        acc[0] = __hadd2(acc[0], t10); acc[1] = __hadd2(acc[1], t11);
        acc[2] = __hadd2(acc[2], t12); acc[3] = __hadd2(acc[3], t13);
        acc[4] = __hadd2(acc[4], t14);
        acc[0] = __hadd2(acc[0], t20); acc[1] = __hadd2(acc[1], t21);
        acc[2] = __hadd2(acc[2], t22); acc[3] = __hadd2(acc[3], t23);
        acc[4] = __hadd2(acc[4], t24);
        acc[0] = __hadd2(acc[0], t30); acc[1] = __hadd2(acc[1], t31);
        acc[2] = __hadd2(acc[2], t32); acc[3] = __hadd2(acc[3], t33);
        acc[4] = __hadd2(acc[4], t34);
    }
    {   // tail pair: s = 24, 25
        int j0 = N_DENSE + 24 * SPARSE_DIM + (int)xr[N_DENSE + 24];
        int j1 = N_DENSE + 25 * SPARSE_DIM + (int)xr[N_DENSE + 25];
        const __half2* b0 = vb + (size_t)j0 * ROW_DW + l;
        const __half2* b1 = vb + (size_t)j1 * ROW_DW + l;
        __half2 t00 = b0[0], t01 = b0[64], t02 = b0[128], t03 = b0[192], t04 = b0[256];
        __half2 t10 = b1[0], t11 = b1[64], t12 = b1[128], t13 = b1[192], t14 = b1[256];
        lin += w[j0] + w[j1];
        acc[0] = __hadd2(acc[0], t00); acc[1] = __hadd2(acc[1], t01);
        acc[2] = __hadd2(acc[2], t02); acc[3] = __hadd2(acc[3], t03);
        acc[4] = __hadd2(acc[4], t04);
        acc[0] = __hadd2(acc[0], t10); acc[1] = __hadd2(acc[1], t11);
        acc[2] = __hadd2(acc[2], t12); acc[3] = __hadd2(acc[3], t13);
        acc[4] = __hadd2(acc[4], t14);
    }

    // ---- reduction (f32) ----
    float sx = 0.f, sy = 0.f, qx = 0.f, qy = 0.f;
#pragma unroll
    for (int m = 0; m < 5; ++m) {
        float ax = __low2float(acc[m]);
        float ay = __high2float(acc[m]);
        sx += ax; sy += ay;
        qx = fmaf(ax, ax, qx);
        qy = fmaf(ay, ay, qy);
    }
#pragma unroll
    for (int mask = 8; mask <= 32; mask <<= 1) {
        sx += __shfl_xor(sx, mask);
        sy += __shfl_xor(sy, mask);
        qx += __shfl_xor(qx, mask);
        qy += __shfl_xor(qy, mask);
    }
    float c = (sx * sx - qx) + (sy * sy - qy);
    c += __shfl_xor(c, 1);
    c += __shfl_xor(c, 2);
    c += __shfl_xor(c, 4);

    float logit = lin + 0.5f * c;
    if (l == 0) out[row] = 1.f / (1.f + expf(-logit));
}

// ---------------- fp32 fallback (round-1 kernel, 16 lanes/row) --------------
#define ROW_Q (ROW_F / 4)
__global__ __launch_bounds__(256) void ffm_fp32(
    const float* __restrict__ x, const float* __restrict__ w,
    const float* __restrict__ bias, const float* __restrict__ v,
    float* __restrict__ out, int B)
{
    __shared__ float ldsDense[N_DENSE * ROW_F];
    const float4* v4 = reinterpret_cast<const float4*>(v);
    float4* lds4 = reinterpret_cast<float4*>(ldsDense);
    for (int i = threadIdx.x; i < N_DENSE * ROW_Q; i += 256) lds4[i] = v4[i];
    __syncthreads();

    const int g = threadIdx.x >> 4, l = threadIdx.x & 15;
    const int row = blockIdx.x * 16 + g;
    if (row >= B) return;
    const float* xr = x + row * (N_DENSE + N_SPARSE);

    float4 acc[10];
#pragma unroll
    for (int i = 0; i < 10; ++i) acc[i] = make_float4(0.f, 0.f, 0.f, 0.f);
#pragma unroll
    for (int j = 0; j < N_DENSE; ++j) {
        float xv = xr[j];
        const float4* b = lds4 + j * ROW_Q;
#pragma unroll
        for (int i = 0; i < 10; ++i)
            if (i < 9 || l < 12) {
                float4 tt = b[l + 16 * i];
                acc[i].x += xv * tt.x; acc[i].y += xv * tt.y;
                acc[i].z += xv * tt.z; acc[i].w += xv * tt.w;
            }
    }
    int nidx[N_SPARSE];
#pragma unroll
    for (int s = 0; s < N_SPARSE; ++s)
        nidx[s] = N_DENSE + s * SPARSE_DIM + (int)xr[N_DENSE + s];
    for (int s = 0; s < N_SPARSE; ++s) {
        const float4* b = v4 + (size_t)nidx[s] * ROW_Q;
#pragma unroll
        for (int i = 0; i < 10; ++i)
            if (i < 9 || l < 12) {
                float4 tt = b[l + 16 * i];
                acc[i].x += tt.x; acc[i].y += tt.y; acc[i].z += tt.z; acc[i].w += tt.w;
            }
    }
    float4 s4 = make_float4(0,0,0,0), q4 = make_float4(0,0,0,0);
#pragma unroll
    for (int i = 0; i < 10; ++i) {
        s4.x += acc[i].x; s4.y += acc[i].y; s4.z += acc[i].z; s4.w += acc[i].w;
        q4.x += acc[i].x*acc[i].x; q4.y += acc[i].y*acc[i].y;
        q4.z += acc[i].z*acc[i].z; q4.w += acc[i].w*acc[i].w;
    }
#pragma unroll
    for (int m = 4; m <= 8; m <<= 1) {
        s4.x += __shfl_xor(s4.x,m); s4.y += __shfl_xor(s4.y,m);
        s4.z += __shfl_xor(s4.z,m); s4.w += __shfl_xor(s4.w,m);
        q4.x += __shfl_xor(q4.x,m); q4.y += __shfl_xor(q4.y,m);
        q4.z += __shfl_xor(q4.z,m); q4.w += __shfl_xor(q4.w,m);
    }
    float c = (s4.x*s4.x - q4.x) + (s4.y*s4.y - q4.y) +
              (s4.z*s4.z - q4.z) + (s4.w*s4.w - q4.w);
    c += __shfl_xor(c,1); c += __shfl_xor(c,2);
    float lin = bias[0];
#pragma unroll
    for (int j = 0; j < N_DENSE; ++j) lin += xr[j]*w[j];
#pragma unroll
    for (int s = 0; s < N_SPARSE; ++s) lin += w[nidx[s]];
    float logit = lin + 0.5f*c;
    if (l == 0) out[row] = 1.f/(1.f+expf(-logit));
}

extern "C" void kernel_launch(void* const* d_in, const int* in_sizes, int n_in,
                              void* d_out, int out_size, void* d_ws, size_t ws_size,
                              hipStream_t stream) {
    const float* x    = (const float*)d_in[0];
    const float* w    = (const float*)d_in[1];
    const float* bias = (const float*)d_in[2];
    const float* v    = (const float*)d_in[3];
    float* out = (float*)d_out;

    int B = in_sizes[0] / (N_DENSE + N_SPARSE);
    size_t need = (size_t)N_FEATURES * ROW_DW * sizeof(__half2);  // 3,344,640 B

    if (ws_size >= need) {
        int cvt_grid = (CVT_TOTAL + 255) / 256;   // 1634 blocks
        cvt_pad_f16v<<<cvt_grid, 256, 0, stream>>>(v, (uint2*)d_ws);
        int grid = (B + ROWS_PER_BLOCK - 1) / ROWS_PER_BLOCK;
        ffm_v14<<<grid, THREADS, 0, stream>>>(
            x, w, bias, (const __half2*)d_ws, out, B);
    } else {
        int grid = (B + 15) / 16;
        ffm_fp32<<<grid, 256, 0, stream>>>(x, w, bias, v, out, B);
    }
}